// Round 1
// 789.039 us; speedup vs baseline: 1.0127x; 1.0127x over previous
//
#include <hip/hip_runtime.h>
#include <math.h>

#define NA 50000
#define NP 1000000
#define OUTF 66
#define SCAN_BLOCKS 196  // ceil(50000/256)
#define ATB 16           // atoms per k_atoms block (NA = 16*3125 exactly)
#define TSTR 516         // T atom stride (floats): 512+4 -> lanes spread banks

// ---------------------------------------------------------------------------
// Workspace (4-byte elems), ~11.4 MB:
//   cnt[NA], offs[NA], curs[NA], blkS[256], sortedP[NP] (packed p<<4 | i&15),
//   S[NA] f32, vec[NA*32] f32
// ---------------------------------------------------------------------------

__global__ void k_hist(const int* __restrict__ idxj, int* __restrict__ cnt) {
    int p = blockIdx.x * 256 + threadIdx.x;
    if (p < NP) atomicAdd(&cnt[idxj[p]], 1);
}

__global__ __launch_bounds__(256) void k_scanA(const int* __restrict__ cnt,
                                               int* __restrict__ blkS) {
    __shared__ int sh[256];
    int t = threadIdx.x;
    int i = blockIdx.x * 256 + t;
    sh[t] = (i < NA) ? cnt[i] : 0;
    __syncthreads();
    for (int d = 128; d > 0; d >>= 1) {
        if (t < d) sh[t] += sh[t + d];
        __syncthreads();
    }
    if (t == 0) blkS[blockIdx.x] = sh[0];
}

__global__ __launch_bounds__(256) void k_scanB(int* __restrict__ blkS) {
    __shared__ int sh[256];
    int t = threadIdx.x;
    sh[t] = (t < SCAN_BLOCKS) ? blkS[t] : 0;
    __syncthreads();
    for (int d = 1; d < 256; d <<= 1) {
        int x = (t >= d) ? sh[t - d] : 0;
        __syncthreads();
        sh[t] += x;
        __syncthreads();
    }
    int e = (t == 0) ? 0 : sh[t - 1];
    if (t < SCAN_BLOCKS) blkS[t] = e;
}

__global__ __launch_bounds__(256) void k_scanC(const int* __restrict__ cnt,
                                               const int* __restrict__ blkS,
                                               int* __restrict__ offs,
                                               int* __restrict__ curs) {
    __shared__ int sh[256];
    int t = threadIdx.x;
    int i = blockIdx.x * 256 + t;
    sh[t] = (i < NA) ? cnt[i] : 0;
    __syncthreads();
    for (int d = 1; d < 256; d <<= 1) {
        int x = (t >= d) ? sh[t - d] : 0;
        __syncthreads();
        sh[t] += x;
        __syncthreads();
    }
    int excl = ((t == 0) ? 0 : sh[t - 1]) + blkS[blockIdx.x];
    if (i < NA) { offs[i] = excl; curs[i] = excl; }
}

__global__ void k_scatter(const int* __restrict__ idxj, int* __restrict__ curs,
                          int* __restrict__ sortedP) {
    int p = blockIdx.x * 256 + threadIdx.x;
    if (p < NP) {
        int i = idxj[p];
        int pos = atomicAdd(&curs[i], 1);
        sortedP[pos] = (p << 4) | (i & 15);  // block-local atom id rides along
    }
}

// ---------------------------------------------------------------------------
// k_atoms: 16 atoms/block, 256 threads.
// Phase B: T[at][h][g] into LDS, atom stride 516 (=4 mod 32: conflict-free
// reads later; same-atom lanes broadcast).
// Phase C: ONE LANE = ONE PAIR. Lane loads its pair's gv row into 12 NAMED
// float4 registers (48 VGPRs, forced resident), loops h=0..31 reading T via
// ds_read_b128 (bank-spread), e -> pair-merged ds_add into vecS.
// __launch_bounds__(256, 4): LDS already caps us at 4 blocks/CU (16 waves/CU),
// so grant the register allocator the full 128-VGPR budget -- the previous
// build allocated only 52 VGPRs and demoted the 48-float gv row to scratch,
// making the kernel scratch-latency-bound (VALUBusy 42%, everything else idle).
// ---------------------------------------------------------------------------
__global__ __launch_bounds__(256, 4) void k_atoms(const float* __restrict__ emb,
                                                  const float* __restrict__ agh,
                                                  const float* __restrict__ gs,
                                                  const float* __restrict__ gv,
                                                  const int* __restrict__ sortedP,
                                                  const int* __restrict__ offs,
                                                  float* __restrict__ S,
                                                  float* __restrict__ vec) {
    __shared__ float T_lds[ATB * TSTR];   // 33.0 KB
    __shared__ float embS[ATB * 64];      // 4 KB
    __shared__ float vecS[ATB * 33];      // stride 33 -> ds_add banks spread
    __shared__ float sS[ATB];
    const int t = threadIdx.x;
    const int atom0 = blockIdx.x * ATB;

    for (int k = t; k < ATB * 33; k += 256) vecS[k] = 0.f;
    if (t < ATB) sS[t] = 0.f;
    for (int k = t; k < ATB * 64; k += 256) embS[k] = emb[(size_t)atom0 * 64 + k];
    __syncthreads();

    {   // ---- T phase: thread owns agh columns c0 = t, c1 = t+256
        float acc0[ATB], acc1[ATB];
#pragma unroll
        for (int at = 0; at < ATB; ++at) { acc0[at] = 0.f; acc1[at] = 0.f; }
        const int c0 = t, c1 = t + 256;
        for (int a = 0; a < 64; ++a) {
            float w0 = agh[a * 512 + c0];
            float w1 = agh[a * 512 + c1];
#pragma unroll
            for (int at = 0; at < ATB; ++at) {
                float e = embS[at * 64 + a];
                acc0[at] += e * w0;
                acc1[at] += e * w1;
            }
        }
        const int g0 = c0 >> 5, h0 = c0 & 31;   // col = g*32 + h
        const int g1 = c1 >> 5, h1 = c1 & 31;
#pragma unroll
        for (int at = 0; at < ATB; ++at) {
            T_lds[at * TSTR + h0 * 16 + g0] = acc0[at];
            T_lds[at * TSTR + h1 * 16 + g1] = acc1[at];
        }
    }
    __syncthreads();

    const int lane = t & 63;
    const int start = offs[atom0];
    const int end = (blockIdx.x + 1 < 3125) ? offs[atom0 + ATB] : NP;

    for (int kb = start; kb < end; kb += 256) {   // uniform trip count
        const int k = kb + t;
        const bool ok = (k < end);
        const int pk = ok ? sortedP[k] : 0;
        const int p = ok ? (pk >> 4) : 0;
        const int at = pk & 15;
        const int atm = ok ? at : (64 + lane);    // unique -> never merges

        // neighbor-merge setup (sorted pairs cluster by atom)
        const int atn = __shfl_xor(atm, 1);
        const bool same = (atn == atm);
        const bool flush = (!same) || ((lane & 1) == 0);

        // gv row -> 12 NAMED float4 registers (d0: ga*, d1: gb*, d2: gc*)
        const float4* gv4 = (const float4*)(gv + (size_t)p * 48);
        float4 ga0 = gv4[0],  ga1 = gv4[1],  ga2 = gv4[2],  ga3 = gv4[3];
        float4 gb0 = gv4[4],  gb1 = gv4[5],  gb2 = gv4[6],  gb3 = gv4[7];
        float4 gc0 = gv4[8],  gc1 = gv4[9],  gc2 = gv4[10], gc3 = gv4[11];

        // gsum
        const float4* gs4 = (const float4*)(gs + (size_t)p * 16);
        float4 sa = gs4[0], sb = gs4[1], sc = gs4[2], sd = gs4[3];
        float gq = (sa.x + sa.y + sa.z + sa.w) + (sb.x + sb.y + sb.z + sb.w) +
                   (sc.x + sc.y + sc.z + sc.w) + (sd.x + sd.y + sd.z + sd.w);
        float gqn = __shfl_xor(gq, 1);
        float gqm = gq + (same ? gqn : 0.f);
        if (ok && flush) atomicAdd(&sS[at], gqm);

        const float* Tb = &T_lds[at * TSTR];
#pragma unroll 2
        for (int h = 0; h < 32; ++h) {
            const float4* Tr = (const float4*)(Tb + h * 16);
            float4 t0 = Tr[0], t1 = Tr[1], t2 = Tr[2], t3 = Tr[3];
            float v0, v1, v2;
            v0  = ga0.x * t0.x; v1  = gb0.x * t0.x; v2  = gc0.x * t0.x;
            v0 += ga0.y * t0.y; v1 += gb0.y * t0.y; v2 += gc0.y * t0.y;
            v0 += ga0.z * t0.z; v1 += gb0.z * t0.z; v2 += gc0.z * t0.z;
            v0 += ga0.w * t0.w; v1 += gb0.w * t0.w; v2 += gc0.w * t0.w;
            v0 += ga1.x * t1.x; v1 += gb1.x * t1.x; v2 += gc1.x * t1.x;
            v0 += ga1.y * t1.y; v1 += gb1.y * t1.y; v2 += gc1.y * t1.y;
            v0 += ga1.z * t1.z; v1 += gb1.z * t1.z; v2 += gc1.z * t1.z;
            v0 += ga1.w * t1.w; v1 += gb1.w * t1.w; v2 += gc1.w * t1.w;
            v0 += ga2.x * t2.x; v1 += gb2.x * t2.x; v2 += gc2.x * t2.x;
            v0 += ga2.y * t2.y; v1 += gb2.y * t2.y; v2 += gc2.y * t2.y;
            v0 += ga2.z * t2.z; v1 += gb2.z * t2.z; v2 += gc2.z * t2.z;
            v0 += ga2.w * t2.w; v1 += gb2.w * t2.w; v2 += gc2.w * t2.w;
            v0 += ga3.x * t3.x; v1 += gb3.x * t3.x; v2 += gc3.x * t3.x;
            v0 += ga3.y * t3.y; v1 += gb3.y * t3.y; v2 += gc3.y * t3.y;
            v0 += ga3.z * t3.z; v1 += gb3.z * t3.z; v2 += gc3.z * t3.z;
            v0 += ga3.w * t3.w; v1 += gb3.w * t3.w; v2 += gc3.w * t3.w;
            float e = v0 * v0 + v1 * v1 + v2 * v2;
            float en = __shfl_xor(e, 1);
            float em = e + (same ? en : 0.f);
            if (ok && flush) atomicAdd(&vecS[at * 33 + h], em);
        }
    }
    __syncthreads();

    for (int k = t; k < ATB * 32; k += 256) {
        int a = k >> 5, h = k & 31;
        vec[(size_t)(atom0 + a) * 32 + h] = vecS[a * 33 + h];
    }
    if (t < ATB) S[atom0 + t] = sS[t];
}

// ---------------------------------------------------------------------------
// k_mlp: 64 atoms/block, 256 threads, register tile 8 atoms x 4 j per thread.
// ---------------------------------------------------------------------------
#define MSTR 132
__global__ __launch_bounds__(256) void k_mlp(const float* __restrict__ emb,
                                             const float* __restrict__ q,
                                             const float* __restrict__ S,
                                             const float* __restrict__ vec,
                                             const float* __restrict__ W1,
                                             const float* __restrict__ b1,
                                             const float* __restrict__ W2,
                                             const float* __restrict__ b2,
                                             const float* __restrict__ W3,
                                             const float* __restrict__ b3,
                                             float* __restrict__ out) {
    __shared__ float bufA[64 * MSTR];
    __shared__ float bufB[64 * MSTR];
    const int t = threadIdx.x;
    const int atom0 = blockIdx.x * 64;

    for (int k = t; k < 64 * 97; k += 256) {
        int a = k / 97, c = k - a * 97;
        int i = atom0 + a;
        float val = 0.f;
        if (i < NA) {
            float s = S[i];
            if (c < 64) val = emb[(size_t)i * 64 + c] * s;
            else if (c < 96) val = vec[(size_t)i * 32 + (c - 64)];
            else val = q[i] * s;
        }
        bufA[a * MSTR + c] = val;
    }
    __syncthreads();

    const int jg = t & 31, ag = t >> 5;
    const int j0 = 4 * jg;
    const int abase = ag * 8;
    float acc[8][4];

    // ---- layer 1: K=97, bufA -> bufB
    {
        float4 bb = *(const float4*)&b1[j0];
#pragma unroll
        for (int a = 0; a < 8; ++a) {
            acc[a][0] = bb.x; acc[a][1] = bb.y; acc[a][2] = bb.z; acc[a][3] = bb.w;
        }
        for (int k4 = 0; k4 < 96; k4 += 4) {
            float4 w0 = *(const float4*)&W1[(k4 + 0) * 128 + j0];
            float4 w1 = *(const float4*)&W1[(k4 + 1) * 128 + j0];
            float4 w2 = *(const float4*)&W1[(k4 + 2) * 128 + j0];
            float4 w3 = *(const float4*)&W1[(k4 + 3) * 128 + j0];
#pragma unroll
            for (int a = 0; a < 8; ++a) {
                float4 m = *(const float4*)&bufA[(abase + a) * MSTR + k4];
                acc[a][0] += m.x * w0.x + m.y * w1.x + m.z * w2.x + m.w * w3.x;
                acc[a][1] += m.x * w0.y + m.y * w1.y + m.z * w2.y + m.w * w3.y;
                acc[a][2] += m.x * w0.z + m.y * w1.z + m.z * w2.z + m.w * w3.z;
                acc[a][3] += m.x * w0.w + m.y * w1.w + m.z * w2.w + m.w * w3.w;
            }
        }
        {   // k = 96 remainder
            float4 w = *(const float4*)&W1[96 * 128 + j0];
#pragma unroll
            for (int a = 0; a < 8; ++a) {
                float m = bufA[(abase + a) * MSTR + 96];
                acc[a][0] += m * w.x; acc[a][1] += m * w.y;
                acc[a][2] += m * w.z; acc[a][3] += m * w.w;
            }
        }
#pragma unroll
        for (int a = 0; a < 8; ++a) {
            float4 o;
            o.x = 0.5f * acc[a][0] * (1.f + erff(acc[a][0] * 0.70710678118654752f));
            o.y = 0.5f * acc[a][1] * (1.f + erff(acc[a][1] * 0.70710678118654752f));
            o.z = 0.5f * acc[a][2] * (1.f + erff(acc[a][2] * 0.70710678118654752f));
            o.w = 0.5f * acc[a][3] * (1.f + erff(acc[a][3] * 0.70710678118654752f));
            *(float4*)&bufB[(abase + a) * MSTR + j0] = o;
        }
    }
    __syncthreads();

    // ---- layer 2: K=128, bufB -> bufA
    {
        float4 bb = *(const float4*)&b2[j0];
#pragma unroll
        for (int a = 0; a < 8; ++a) {
            acc[a][0] = bb.x; acc[a][1] = bb.y; acc[a][2] = bb.z; acc[a][3] = bb.w;
        }
        for (int k4 = 0; k4 < 128; k4 += 4) {
            float4 w0 = *(const float4*)&W2[(k4 + 0) * 128 + j0];
            float4 w1 = *(const float4*)&W2[(k4 + 1) * 128 + j0];
            float4 w2 = *(const float4*)&W2[(k4 + 2) * 128 + j0];
            float4 w3 = *(const float4*)&W2[(k4 + 3) * 128 + j0];
#pragma unroll
            for (int a = 0; a < 8; ++a) {
                float4 m = *(const float4*)&bufB[(abase + a) * MSTR + k4];
                acc[a][0] += m.x * w0.x + m.y * w1.x + m.z * w2.x + m.w * w3.x;
                acc[a][1] += m.x * w0.y + m.y * w1.y + m.z * w2.y + m.w * w3.y;
                acc[a][2] += m.x * w0.z + m.y * w1.z + m.z * w2.z + m.w * w3.z;
                acc[a][3] += m.x * w0.w + m.y * w1.w + m.z * w2.w + m.w * w3.w;
            }
        }
#pragma unroll
        for (int a = 0; a < 8; ++a) {
            float4 o;
            o.x = 0.5f * acc[a][0] * (1.f + erff(acc[a][0] * 0.70710678118654752f));
            o.y = 0.5f * acc[a][1] * (1.f + erff(acc[a][1] * 0.70710678118654752f));
            o.z = 0.5f * acc[a][2] * (1.f + erff(acc[a][2] * 0.70710678118654752f));
            o.w = 0.5f * acc[a][3] * (1.f + erff(acc[a][3] * 0.70710678118654752f));
            *(float4*)&bufA[(abase + a) * MSTR + j0] = o;
        }
    }
    __syncthreads();

    // ---- layer 3: K=128, bufA -> out (66 cols; jg>16 idle)
    if (j0 < OUTF) {
#pragma unroll
        for (int a = 0; a < 8; ++a) {
            acc[a][0] = b3[j0];
            acc[a][1] = (j0 + 1 < OUTF) ? b3[j0 + 1] : 0.f;
            acc[a][2] = (j0 + 2 < OUTF) ? b3[j0 + 2] : 0.f;
            acc[a][3] = (j0 + 3 < OUTF) ? b3[j0 + 3] : 0.f;
        }
        for (int k = 0; k < 128; ++k) {
            float w0 = W3[k * OUTF + j0];
            float w1 = (j0 + 1 < OUTF) ? W3[k * OUTF + j0 + 1] : 0.f;
            float w2 = (j0 + 2 < OUTF) ? W3[k * OUTF + j0 + 2] : 0.f;
            float w3 = (j0 + 3 < OUTF) ? W3[k * OUTF + j0 + 3] : 0.f;
#pragma unroll
            for (int a = 0; a < 8; ++a) {
                float m = bufA[(abase + a) * MSTR + k];
                acc[a][0] += m * w0; acc[a][1] += m * w1;
                acc[a][2] += m * w2; acc[a][3] += m * w3;
            }
        }
#pragma unroll
        for (int a = 0; a < 8; ++a) {
            int i = atom0 + abase + a;
            if (i < NA) {
#pragma unroll
                for (int c = 0; c < 4; ++c) {
                    int j = j0 + c;
                    if (j < OUTF) {
                        if (j == 0)
                            out[(size_t)NA * 64 + i] = acc[a][c];        // delta_q
                        else if (j == 1)
                            out[(size_t)NA * 64 + NA + i] = acc[a][c];   // f
                        else
                            out[(size_t)i * 64 + (j - 2)] = acc[a][c];   // delta_a
                    }
                }
            }
        }
    }
}

extern "C" void kernel_launch(void* const* d_in, const int* in_sizes, int n_in,
                              void* d_out, int out_size, void* d_ws, size_t ws_size,
                              hipStream_t stream) {
    const float* emb = (const float*)d_in[0];
    const float* q   = (const float*)d_in[1];
    const float* gs  = (const float*)d_in[2];
    const float* gv  = (const float*)d_in[3];
    const float* agh = (const float*)d_in[4];
    const float* W1  = (const float*)d_in[5];
    const float* b1  = (const float*)d_in[6];
    const float* W2  = (const float*)d_in[7];
    const float* b2  = (const float*)d_in[8];
    const float* W3  = (const float*)d_in[9];
    const float* b3  = (const float*)d_in[10];
    const int* pairs = (const int*)d_in[11];
    const int* idxj  = pairs + NP;  // row 1 of pair_indices

    int*   cnt     = (int*)d_ws;
    int*   offs    = cnt + NA;
    int*   curs    = offs + NA;
    int*   blkS    = curs + NA;
    int*   sortedP = blkS + 256;
    float* S       = (float*)(sortedP + NP);
    float* vec     = S + NA;

    hipMemsetAsync(cnt, 0, NA * sizeof(int), stream);
    k_hist<<<(NP + 255) / 256, 256, 0, stream>>>(idxj, cnt);
    k_scanA<<<SCAN_BLOCKS, 256, 0, stream>>>(cnt, blkS);
    k_scanB<<<1, 256, 0, stream>>>(blkS);
    k_scanC<<<SCAN_BLOCKS, 256, 0, stream>>>(cnt, blkS, offs, curs);
    k_scatter<<<(NP + 255) / 256, 256, 0, stream>>>(idxj, curs, sortedP);
    k_atoms<<<NA / ATB, 256, 0, stream>>>(emb, agh, gs, gv, sortedP, offs, S, vec);
    k_mlp<<<(NA + 63) / 64, 256, 0, stream>>>(emb, q, S, vec,
                                              W1, b1, W2, b2, W3, b3,
                                              (float*)d_out);
}